// Round 1
// baseline (436.112 us; speedup 1.0000x reference)
//
#include <hip/hip_runtime.h>
#include <math.h>
#include <stdint.h>

#define NANCH 49104
#define NCLS 80
#define KSEL 100
#define NFLAT (NCLS * KSEL)
#define PREDC 84
#define NB 8
#define ECAP 128

struct DimsTable { float d[5][9][2]; };

__device__ __forceinline__ uint32_t f2key(float f) {
    uint32_t u = __float_as_uint(f);
    return u ^ (uint32_t((int32_t)u >> 31) | 0x80000000u);
}
__device__ __forceinline__ float key2f(uint32_t k) {
    uint32_t u = (k & 0x80000000u) ? (k ^ 0x80000000u) : ~k;
    return __uint_as_float(u);
}
__device__ __forceinline__ float sigm(float x) { return 1.0f / (1.0f + expf(-x)); }

// ---------------- decode one box (matches reference _decode bit-for-bit ops) ----
__device__ __forceinline__ void decode_box(const float* __restrict__ prow, int n,
                                           const DimsTable& dt, float box[4]) {
    int lev, base, fw, stride;
    if (n < 36864)      { lev = 0; base = 0;     fw = 64; stride = 8;   }
    else if (n < 46080) { lev = 1; base = 36864; fw = 32; stride = 16;  }
    else if (n < 48384) { lev = 2; base = 46080; fw = 16; stride = 32;  }
    else if (n < 48960) { lev = 3; base = 48384; fw = 8;  stride = 64;  }
    else                { lev = 4; base = 48960; fw = 4;  stride = 128; }
    int i = n - base;
    int k = i % 9;
    int cell = i / 9;
    int xq = cell % fw, yq = cell / fw;
    float cx = ((float)xq + 0.5f) * (float)stride;
    float cy = ((float)yq + 0.5f) * (float)stride;
    float aw = dt.d[lev][k][0];
    float ah = dt.d[lev][k][1];
    float tx = __fmul_rn(prow[0], 0.1f);
    float ty = __fmul_rn(prow[1], 0.1f);
    float tw = __fmul_rn(prow[2], 0.2f);
    float th = __fmul_rn(prow[3], 0.2f);
    float px = __fadd_rn(__fmul_rn(tx, aw), cx);
    float py = __fadd_rn(__fmul_rn(ty, ah), cy);
    float pw = __fmul_rn(expf(tw), aw);
    float ph = __fmul_rn(expf(th), ah);
    float hw = __fmul_rn(pw, 0.5f);
    float hh = __fmul_rn(ph, 0.5f);
    box[0] = __fsub_rn(px, hw);
    box[1] = __fsub_rn(py, hh);
    box[2] = __fadd_rn(px, hw);
    box[3] = __fadd_rn(py, hh);
}

// ---------------- shared state for block-level exact top-100 -------------------
struct SelSh {
    int hist[4][2048];      // 4 wave-private copies for pass 0 (contention)
    int partial[256];
    int suffix[256];
    uint32_t candKey[KSEL];
    int candIdx[KSEL];
    uint32_t eIdx[ECAP];
    uint32_t sKey[KSEL];
    int sIdx[KSEL];
    int cntG, cntE, krem, newkrem, digit, flast, rmin;
    uint32_t prefix, thrKey;
};

// Exact top-100 (descending by value, ties -> smaller index), 256 threads.
template <typename F>
__device__ void block_top100(F loadf, int N, SelSh& sh) {
    const int tid = threadIdx.x;
    const int wid = tid >> 6;
    if (tid == 0) { sh.krem = KSEL; sh.prefix = 0; }

    for (int pass = 0; pass < 3; ++pass) {
        const int bins   = (pass == 2) ? 1024 : 2048;
        const int dshift = (pass == 0) ? 21 : (pass == 1 ? 10 : 0);
        const int fshift = (pass == 1) ? 21 : 10;      // filter shift (pass>0)
        const int dmask  = bins - 1;
        const bool multi = (pass == 0);
        // zero
        if (multi) { for (int j = tid; j < 4 * 2048; j += 256) ((int*)sh.hist)[j] = 0; }
        else       { for (int j = tid; j < bins; j += 256) sh.hist[0][j] = 0; }
        __syncthreads();
        const uint32_t pref = sh.prefix;
        for (int i = tid; i < N; i += 256) {
            uint32_t key = f2key(loadf(i));
            if (pass == 0) {
                atomicAdd(&sh.hist[wid][(key >> dshift) & dmask], 1);
            } else if ((key >> fshift) == pref) {
                atomicAdd(&sh.hist[0][(key >> dshift) & dmask], 1);
            }
        }
        __syncthreads();
        if (multi) {
            for (int j = tid; j < bins; j += 256)
                sh.hist[0][j] += sh.hist[1][j] + sh.hist[2][j] + sh.hist[3][j];
            __syncthreads();
        }
        const int cpb = bins / 256;
        const int base = tid * cpb;
        int lsum = 0;
        for (int j = 0; j < cpb; ++j) lsum += sh.hist[0][base + j];
        sh.partial[tid] = lsum;
        __syncthreads();
        if (tid == 0) {
            int run = 0;
            for (int t = 255; t >= 0; --t) { sh.suffix[t] = run; run += sh.partial[t]; }
        }
        __syncthreads();
        {
            int cum = sh.suffix[tid];
            const int krem = sh.krem;
            for (int j = cpb - 1; j >= 0; --j) {
                int cnt = sh.hist[0][base + j];
                if (cnt > 0 && cum < krem && cum + cnt >= krem) {
                    sh.digit = base + j;
                    sh.newkrem = krem - cum;
                }
                cum += cnt;
            }
        }
        __syncthreads();
        if (tid == 0) {
            sh.krem = sh.newkrem;
            if (pass == 0)      sh.prefix = (uint32_t)sh.digit;
            else if (pass == 1) sh.prefix = (sh.prefix << 11) | (uint32_t)sh.digit;
            else                sh.thrKey = (sh.prefix << 10) | (uint32_t)sh.digit;
        }
        __syncthreads();
    }

    // ---- collect: all strictly-greater, plus `need` smallest-index equals ----
    if (tid == 0) { sh.cntG = 0; sh.cntE = 0; }
    __syncthreads();
    const uint32_t thr = sh.thrKey;
    for (int i = tid; i < N; i += 256) {
        uint32_t key = f2key(loadf(i));
        if (key > thr) {
            int g = atomicAdd(&sh.cntG, 1);
            sh.candKey[g] = key; sh.candIdx[g] = i;   // g <= 98 guaranteed
        } else if (key == thr) {
            int e = atomicAdd(&sh.cntE, 1);
            if (e < ECAP) sh.eIdx[e] = (uint32_t)i;
        }
    }
    __syncthreads();
    const int need = sh.krem;
    const int G = KSEL - need;
    if (sh.cntE <= ECAP) {
        const int ce = sh.cntE;
        if (tid < ce) {
            uint32_t my = sh.eIdx[tid];
            int rank = 0;
            for (int j = 0; j < ce; ++j) rank += (sh.eIdx[j] < my);
            if (rank < need) { sh.candKey[G + rank] = thr; sh.candIdx[G + rank] = (int)my; }
        }
    } else {
        // pathological tie overflow: iteratively take smallest indices
        if (tid == 0) sh.flast = -1;
        __syncthreads();
        for (int t = 0; t < need; ++t) {
            if (tid == 0) sh.rmin = 0x7FFFFFFF;
            __syncthreads();
            const int fl = sh.flast;
            int lmin = 0x7FFFFFFF;
            for (int i = tid; i < N; i += 256)
                if (i > fl && f2key(loadf(i)) == thr) { lmin = min(lmin, i); }
            atomicMin(&sh.rmin, lmin);
            __syncthreads();
            if (tid == 0) { sh.candKey[G + t] = thr; sh.candIdx[G + t] = sh.rmin; sh.flast = sh.rmin; }
            __syncthreads();
        }
    }
    __syncthreads();
    // ---- rank-sort the 100 (desc by key, ties asc by idx) ----
    if (tid < KSEL) {
        uint32_t mk = sh.candKey[tid]; int mi = sh.candIdx[tid];
        int rank = 0;
        for (int j = 0; j < KSEL; ++j) {
            uint32_t kj = sh.candKey[j]; int ij = sh.candIdx[j];
            rank += (kj > mk) || (kj == mk && ij < mi);
        }
        sh.sKey[rank] = mk; sh.sIdx[rank] = mi;
    }
    __syncthreads();
}

// ---------------- kernel A: sigmoid + transpose to [b][c][n] -------------------
__global__ __launch_bounds__(256) void sigmoid_transpose(
    const float* __restrict__ pred, float* __restrict__ scores_t, int b0) {
    int n = blockIdx.x * 256 + threadIdx.x;
    int bl = blockIdx.y;
    int b = b0 + bl;
    if (n >= NANCH) return;
    const float4* row = reinterpret_cast<const float4*>(
        pred + ((size_t)b * NANCH + n) * PREDC + 4);
    float* ob = scores_t + (size_t)bl * NCLS * NANCH + n;
#pragma unroll
    for (int q = 0; q < 20; ++q) {
        float4 v = row[q];
        ob[(size_t)(4 * q + 0) * NANCH] = sigm(v.x);
        ob[(size_t)(4 * q + 1) * NANCH] = sigm(v.y);
        ob[(size_t)(4 * q + 2) * NANCH] = sigm(v.z);
        ob[(size_t)(4 * q + 3) * NANCH] = sigm(v.w);
    }
}

// ---------------- kernel B: per-(b,c) top-100 + NMS ----------------------------
// MODE 0: read transposed scores. MODE 1: direct strided read from predictions.
template <int MODE>
__global__ __launch_bounds__(256) void nms_per_class(
    const float* __restrict__ pred, const float* __restrict__ scores_t,
    float* __restrict__ cls_boxes, float* __restrict__ cls_scores,
    int b0, DimsTable dt) {
    __shared__ SelSh sh;
    __shared__ float sbox[KSEL][4];
    __shared__ float sarea[KSEL];
    __shared__ int keep[KSEL];
    const int c = blockIdx.x;
    const int bl = blockIdx.y;
    const int b = b0 + bl;
    const int tid = threadIdx.x;

    if (MODE == 0) {
        const float* src = scores_t + ((size_t)bl * NCLS + c) * NANCH;
        auto loader = [src](int i) { return src[i]; };
        block_top100(loader, NANCH, sh);
    } else {
        const float* src = pred + ((size_t)b * NANCH) * PREDC + 4 + c;
        auto loader = [src](int i) { return sigm(src[(size_t)i * PREDC]); };
        block_top100(loader, NANCH, sh);
    }

    if (tid < KSEL) {
        int n = sh.sIdx[tid];
        const float* prow = pred + ((size_t)b * NANCH + n) * PREDC;
        float bx[4];
        decode_box(prow, n, dt, bx);
        sbox[tid][0] = bx[0]; sbox[tid][1] = bx[1];
        sbox[tid][2] = bx[2]; sbox[tid][3] = bx[3];
        sarea[tid] = __fmul_rn(__fsub_rn(bx[2], bx[0]), __fsub_rn(bx[3], bx[1]));
        keep[tid] = (key2f(sh.sKey[tid]) > 0.05f) ? 1 : 0;
    }
    __syncthreads();
    for (int i = 0; i < KSEL; ++i) {
        if (keep[i] && tid < KSEL && tid > i && keep[tid]) {
            float x1 = fmaxf(sbox[i][0], sbox[tid][0]);
            float y1 = fmaxf(sbox[i][1], sbox[tid][1]);
            float x2 = fminf(sbox[i][2], sbox[tid][2]);
            float y2 = fminf(sbox[i][3], sbox[tid][3]);
            float iw = fmaxf(__fsub_rn(x2, x1), 0.0f);
            float ih = fmaxf(__fsub_rn(y2, y1), 0.0f);
            float inter = __fmul_rn(iw, ih);
            float uni = __fsub_rn(__fadd_rn(sarea[i], sarea[tid]), inter);
            float iou = __fdiv_rn(inter, fmaxf(uni, 1e-8f));
            if (iou > 0.5f) keep[tid] = 0;
        }
        __syncthreads();
    }
    if (tid < KSEL) {
        size_t o = ((size_t)b * NCLS + c) * KSEL + tid;
        cls_scores[o] = keep[tid] ? key2f(sh.sKey[tid]) : -1.0f;
        float4 bb = make_float4(sbox[tid][0], sbox[tid][1], sbox[tid][2], sbox[tid][3]);
        reinterpret_cast<float4*>(cls_boxes)[o] = bb;
    }
}

// ---------------- kernel C: per-batch final top-100 + mask ---------------------
__global__ __launch_bounds__(256) void final_topk(
    const float* __restrict__ cls_boxes, const float* __restrict__ cls_scores,
    float* __restrict__ out) {
    __shared__ SelSh sh;
    __shared__ int validCnt;
    const int b = blockIdx.x;
    const int tid = threadIdx.x;
    const float* src = cls_scores + (size_t)b * NFLAT;
    auto loader = [src](int i) { return src[i]; };
    block_top100(loader, NFLAT, sh);
    if (tid == 0) validCnt = 0;
    __syncthreads();
    if (tid < KSEL) {
        float v = key2f(sh.sKey[tid]);
        int fi = sh.sIdx[tid];
        bool m = v > 0.0f;
        if (m) atomicAdd(&validCnt, 1);
        float4 bb = reinterpret_cast<const float4*>(cls_boxes)[(size_t)b * NFLAT + fi];
        float4 ob = m ? bb : make_float4(0.f, 0.f, 0.f, 0.f);
        reinterpret_cast<float4*>(out)[(size_t)b * KSEL + tid] = ob;       // boxes
        out[NB * KSEL * 4 + b * KSEL + tid] = m ? v : 0.0f;                // scores
        out[NB * KSEL * 5 + b * KSEL + tid] = m ? (float)(fi / KSEL) : 0.0f; // classes
    }
    __syncthreads();
    if (tid == 0) out[NB * KSEL * 6 + b] = (float)validCnt;                // valid
}

// ---------------- host launcher ------------------------------------------------
extern "C" void kernel_launch(void* const* d_in, const int* in_sizes, int n_in,
                              void* d_out, int out_size, void* d_ws, size_t ws_size,
                              hipStream_t stream) {
    const float* pred = (const float*)d_in[1];
    float* out = (float*)d_out;

    // anchor dims table, double math mirroring numpy reference
    DimsTable dt;
    const double areasd[5] = {1024.0, 4096.0, 16384.0, 65536.0, 262144.0};
    const double ratios[3] = {0.5, 1.0, 2.0};
    const double scales[3] = {1.0, pow(2.0, 1.0 / 3.0), pow(2.0, 2.0 / 3.0)};
    for (int l = 0; l < 5; ++l)
        for (int ri = 0; ri < 3; ++ri) {
            double ah = sqrt(areasd[l] / ratios[ri]);
            double aw = areasd[l] / ah;
            for (int si = 0; si < 3; ++si) {
                dt.d[l][ri * 3 + si][0] = (float)(aw * scales[si]);
                dt.d[l][ri * 3 + si][1] = (float)(ah * scales[si]);
            }
        }

    float* ws = (float*)d_ws;
    const size_t cb_sz = (size_t)NB * NCLS * KSEL * 4;
    const size_t cs_sz = (size_t)NB * NCLS * KSEL;
    float* cls_boxes = ws;
    float* cls_scores = ws + cb_sz;
    float* scores_t = cls_scores + cs_sz;
    const size_t ws_f = ws_size / 4;
    const size_t perb = (size_t)NCLS * NANCH;
    int G = 0;
    if (ws_f > cb_sz + cs_sz) G = (int)((ws_f - cb_sz - cs_sz) / perb);
    if (G > NB) G = NB;

    if (G >= 1) {
        for (int b0 = 0; b0 < NB; b0 += G) {
            int gb = (G < NB - b0) ? G : (NB - b0);
            dim3 ga((NANCH + 255) / 256, gb);
            sigmoid_transpose<<<ga, 256, 0, stream>>>(pred, scores_t, b0);
            dim3 gbb(NCLS, gb);
            nms_per_class<0><<<gbb, 256, 0, stream>>>(pred, scores_t, cls_boxes,
                                                      cls_scores, b0, dt);
        }
    } else {
        dim3 gbb(NCLS, NB);
        nms_per_class<1><<<gbb, 256, 0, stream>>>(pred, nullptr, cls_boxes,
                                                  cls_scores, 0, dt);
    }
    final_topk<<<NB, 256, 0, stream>>>(cls_boxes, cls_scores, out);
}